// Round 12
// baseline (31.891 us; speedup 1.0000x reference)
//
#include <hip/hip_runtime.h>

#define NBATCH 4096
#define NT 2048
#define NP 1024
#define NTH 512
#define NW  (NTH / 64)    // 8 waves
#define EPT 4             // NT elements per thread
#define PPT 2             // NP items per thread
#define MSZ 1022          // interior system size (NP-2)
#define KT 4              // conv half-width
#define IMGW 14           // boundary image reach

__global__ __launch_bounds__(NTH, 8) void w2loss_kernel(
    const float* __restrict__ f,
    const float* __restrict__ obs,
    float* __restrict__ partial)
{
    __shared__ float2 sQM[NP];           // .x = q_k, .y = M_k
    __shared__ float  sRp[MSZ + 2 * KT]; // zero-padded rhs
    __shared__ float  sH[NTH];           // prev-thread last square handoff
    __shared__ float  sPow[IMGW];        // rho^d
    __shared__ float  sWSA[NW], sWSB[NW];
    __shared__ float  sSqA[2], sSqB[2];
    __shared__ float  sRed[NW];

    const int tid  = threadIdx.x;
    const int lane = tid & 63;
    const int wid  = tid >> 6;
    const int b    = blockIdx.x;
    const int base = tid * EPT;

    const float dt      = 0.001f;
    const float half_dt = 0.0005f;
    const float h       = 0.00097751710654936461f;  // 1/1023
    const float inv_h   = 1023.0f;
    const float inv_h2  = 1046529.0f;               // 1023^2
    const float h6      = h * (1.0f / 6.0f);
    const float ih6     = inv_h * (1.0f / 6.0f);

    const float* orow = obs + (size_t)b * NT;
    const float* frow = f   + (size_t)b * NT;
    float4 o0 = *reinterpret_cast<const float4*>(orow + base);
    float4 g0 = *reinterpret_cast<const float4*>(frow + base);

    if (tid < IMGW) {
        const float rho = -0.26794919243112270f;
        float v = 1.0f;
        for (int i = 0; i < tid; ++i) v *= rho;
        sPow[tid] = v;
    }
    if (tid < KT) { sRp[tid] = 0.0f; sRp[KT + MSZ + tid] = 0.0f; }

    // ---- squares + per-thread prefixes for BOTH rows ----
    float prefA[EPT], prefB[EPT];
    prefA[0] = o0.x*o0.x;
    prefA[1] = prefA[0] + o0.y*o0.y;
    prefA[2] = prefA[1] + o0.z*o0.z;
    prefA[3] = prefA[2] + o0.w*o0.w;
    prefB[0] = g0.x*g0.x;
    prefB[1] = prefB[0] + g0.y*g0.y;
    prefB[2] = prefB[1] + g0.z*g0.z;
    prefB[3] = prefB[2] + g0.w*g0.w;
    float sqAL = o0.w * o0.w;
    float sqBL = g0.w * g0.w;
    sH[tid] = sqAL;                      // handoff BEFORE B1 (read after B1)

    // ---- interleaved wave scans (2x ILP) ----
    float tsA = prefA[EPT - 1], tsB = prefB[EPT - 1];
    float wsA = tsA, wsB = tsB;
#pragma unroll
    for (int off = 1; off < 64; off <<= 1) {
        float uA = __shfl_up(wsA, off);
        float uB = __shfl_up(wsB, off);
        if (lane >= off) { wsA += uA; wsB += uB; }
    }
    if (lane == 63) { sWSA[wid] = wsA; sWSB[wid] = wsB; }
    if (tid == 0)       { sSqA[0] = prefA[0]; sSqB[0] = prefB[0]; }
    if (tid == NTH - 1) { sSqA[1] = sqAL;     sSqB[1] = sqBL; }
    __syncthreads();                                            // B1

    float exclA = wsA - tsA, exclB = wsB - tsB;
    float totA = 0.0f, totB = 0.0f;
#pragma unroll
    for (int w = 0; w < NW; ++w) {
        float a = sWSA[w], bv = sWSB[w];
        if (w < wid) { exclA += a; exclB += bv; }
        totA += a; totB += bv;
    }
    float sq0A = sSqA[0], sq0B = sSqB[0];
    float invSA = 1.0f / (half_dt * (2.0f * totA - sSqA[1] - sq0A));
    float invSB = 1.0f / (half_dt * (2.0f * totB - sSqB[1] - sq0B));

    // ---- inverse-CDF by forward scatter: j claims p_k in (c_{j-1}, c_j] ----
    {
        float cm;
        if (tid == 0) cm = -1.0f;
        else {
            float sqprev = sH[tid - 1];
            cm = half_dt * (((exclA - sqprev) + exclA) - sq0A) * invSA;
        }
        float Pm = exclA;
#pragma unroll
        for (int e = 0; e < EPT; ++e) {
            int j = base + e;
            float Pj = exclA + prefA[e];
            float cc = (j == 0) ? 0.0f : half_dt * (Pm + Pj - sq0A) * invSA;
            int kLo = (int)floorf(cm * inv_h) + 1;
            int kHi = (int)floorf(cc * inv_h);
            if (kLo < 0) kLo = 0;
            if (j == NT - 1) kHi = NP - 1;          // guarantee k=1023 coverage
            else {
                if (e == EPT - 1) kHi += 1;         // bridge thread-boundary ulp gap
                if (kHi > NP - 1) kHi = NP - 1;
            }
            float qv = (float)j * dt;
            for (int k = kLo; k <= kHi; ++k) sQM[k].x = qv;
            cm = cc;
            Pm = Pj;
        }
    }
    __syncthreads();                                            // B2

    // ---- rhs (strided, conflict-free) ----
#pragma unroll
    for (int kk = 0; kk < PPT; ++kk) {
        int i = tid + kk * NTH;
        if (i < MSZ)
            sRp[KT + i] = 6.0f * (sQM[i].x - 2.0f * sQM[i + 1].x + sQM[i + 2].x) * inv_h2;
    }
    __syncthreads();                                            // B3

    // ---- tridiagonal solve: constant-tap conv + redundant boundary images ----
    {
        const float Cg = 0.28867513459481288f; // 1/(2*sqrt(3))
        const float CP[KT + 1] = {
            1.0f, -0.26794919243112270f, 0.071796769724490830f,
            -0.019237886466840586f, 0.0051547761428899979f };
#pragma unroll
        for (int kk = 0; kk < PPT; ++kk) {
            int i = tid + kk * NTH;
            if (i < MSZ) {
                float acc = 0.0f;
#pragma unroll
                for (int d = -KT; d <= KT; ++d) {
                    int ad = d < 0 ? -d : d;
                    acc += CP[ad] * sRp[KT + i + d];
                }
                if (i + 1 < IMGW) {
                    float t1 = 0.0f;
#pragma unroll
                    for (int k2 = 0; k2 < IMGW - 1; ++k2) t1 += sPow[k2 + 1] * sRp[KT + k2];
                    acc -= sPow[i + 1] * t1;
                }
                if (MSZ - i < IMGW) {
                    float t2 = 0.0f;
#pragma unroll
                    for (int k2 = MSZ - IMGW + 1; k2 < MSZ; ++k2) t2 += sPow[MSZ - k2] * sRp[KT + k2];
                    acc -= sPow[MSZ - i] * t2;
                }
                sQM[i + 1].y = Cg * acc;
            }
        }
    }
    if (tid == 0) { sQM[0].y = 0.0f; sQM[NP - 1].y = 0.0f; }
    __syncthreads();                                            // B4

    // ---- Phase B: F in registers, float2 gathers, inline coeffs, integrate ----
    float local = 0.0f;
    float term0 = 0.0f, termL = 0.0f;
    {
        const float c1B = half_dt * invSB;
        const float K0  = (2.0f * exclB - sq0B) * c1B;
        float tj = (float)base * dt;
#pragma unroll
        for (int e = 0; e < EPT; ++e) {
            float Gj = (e ? prefB[e - 1] : 0.0f) + prefB[e];
            float Fj = __builtin_fmaf(Gj, c1B, K0);   // ~exact 0 at j==0
            float sqe = e ? (prefB[e] - prefB[e - 1]) : prefB[0];
            float kf = Fj * inv_h;
            kf = fminf(fmaxf(kf, 0.0f), 1022.0f);
            int k = (int)kf;
            float s = __builtin_fmaf(-h, (float)k, Fj);
            float2 qm0 = sQM[k];
            float2 qm1 = sQM[k + 1];
            float bco = (qm1.x - qm0.x) * inv_h - (2.0f * qm0.y + qm1.y) * h6;
            float od  = qm0.x + s * (bco + s * (0.5f * qm0.y + s * (qm1.y - qm0.y) * ih6));
            float dd  = tj - od;
            float term = dd * dd * sqe;
            local += term;
            if (e == 0) term0 = term;
            if (e == EPT - 1) termL = term;
            tj += dt;
        }
    }
    if (tid == 0)       local -= 0.5f * term0;   // trapezoid half-weight at j=0
    if (tid == NTH - 1) local -= 0.5f * termL;   // and at j=NT-1

#pragma unroll
    for (int off = 32; off > 0; off >>= 1) local += __shfl_down(local, off);
    if (lane == 0) sRed[wid] = local;
    __syncthreads();                                            // B5
    if (tid == 0) {
        float t = 0.0f;
#pragma unroll
        for (int w = 0; w < NW; ++w) t += sRed[w];
        partial[b] = t * (dt * invSB);
    }
}

// fixed-order deterministic reduction: 64 threads, wave-only (no LDS, no barrier)
__global__ __launch_bounds__(64) void w2loss_reduce(
    const float* __restrict__ partial, float* __restrict__ out)
{
    const int lane = threadIdx.x;
    const float4* p4 = reinterpret_cast<const float4*>(partial);
    float s = 0.0f;
#pragma unroll
    for (int i = 0; i < 16; ++i) {
        float4 v = p4[lane * 16 + i];
        s += v.x + v.y + v.z + v.w;
    }
#pragma unroll
    for (int off = 32; off > 0; off >>= 1) s += __shfl_down(s, off);
    if (lane == 0) out[0] = s;
}

extern "C" void kernel_launch(void* const* d_in, const int* in_sizes, int n_in,
                              void* d_out, int out_size, void* d_ws, size_t ws_size,
                              hipStream_t stream) {
    const float* f   = (const float*)d_in[0];
    const float* obs = (const float*)d_in[1];
    float* out     = (float*)d_out;
    float* partial = (float*)d_ws;   // 4096 floats = 16 KB scratch

    w2loss_kernel<<<NBATCH, NTH, 0, stream>>>(f, obs, partial);
    w2loss_reduce<<<1, 64, 0, stream>>>(partial, out);
}